// Round 1
// baseline (64.115 us; speedup 1.0000x reference)
//
#include <hip/hip_runtime.h>
#include <math.h>

// GaussianImage Cholesky splat render: 1024 gaussians -> (3, 256, 256).
// Strategy: 1 block per 16x16 pixel tile (256 blocks == 256 CUs).
// Each block: (a) projects all N gaussians (4 per thread), (b) culls by
// conservative support bounding box (alpha>=1/255 <=> sigma<=ln(255*op)),
// (c) compacts survivors into LDS, (d) each thread renders its pixel over
// the ~15 surviving gaussians. ~70x work reduction vs dense N x P loop.

constexpr int HH = 256;
constexpr int WW = 256;
constexpr int TILE = 16;
constexpr int MAXG = 1024;          // capacity == N, cannot overflow
constexpr float ALPHA_T = 1.0f / 255.0f;

__global__ __launch_bounds__(256) void gsplat_render(
    const float* __restrict__ xyz,    // (N,2)
    const float* __restrict__ chol,   // (N,3)
    const float* __restrict__ feat,   // (N,3)
    const float* __restrict__ opac,   // (N,1)
    float* __restrict__ out,          // (3,H,W) flat
    int N)
{
    __shared__ float4 cA[MAXG];   // cx, cy, conic_a, conic_b
    __shared__ float4 cB[MAXG];   // conic_c, op, fr, fg
    __shared__ float  cC[MAXG];   // fb
    __shared__ int    s_cnt;

    const int tid = threadIdx.x;
    if (tid == 0) s_cnt = 0;
    __syncthreads();

    const int tx = blockIdx.x & 15;
    const int ty = blockIdx.x >> 4;
    // pixel-center coordinate range covered by this tile
    const float x0c = (float)(tx * TILE) + 0.5f;
    const float x1c = (float)(tx * TILE + TILE - 1) + 0.5f;
    const float y0c = (float)(ty * TILE) + 0.5f;
    const float y1c = (float)(ty * TILE + TILE - 1) + 0.5f;

    // ---- project + cull + compact ----
    for (int i = tid; i < N; i += 256) {
        float mx = tanhf(xyz[2 * i]);
        float my = tanhf(xyz[2 * i + 1]);
        float cx = 0.5f * (float)WW * (mx + 1.0f);
        float cy = 0.5f * (float)HH * (my + 1.0f);
        float l1 = chol[3 * i]     + 0.5f;
        float l2 = chol[3 * i + 1];
        float l3 = chol[3 * i + 2] + 0.5f;
        float a = l1 * l1;
        float b = l1 * l2;
        float c = l2 * l2 + l3 * l3;
        float det = a * c - b * b;
        float ca = c / det;
        float cb = -b / det;
        float cc = a / det;
        float op = opac[i];

        // support: op*exp(-sigma) >= 1/255  <=>  sigma <= ln(255*op) = T
        // ellipse {0.5 d^T Sigma^-1 d <= T}: |dx|max = sqrt(2T)*l1,
        // |dy|max = sqrt(2T*(l2^2+l3^2)). NaN (T<0, det<=0) => compares
        // false => culled, consistent with ref (w=0 there).
        float T   = __logf(255.0f * op);
        float s2T = sqrtf(2.0f * T);
        float rx  = s2T * l1 + 0.05f;           // margin for fp safety
        float ry  = s2T * sqrtf(c) + 0.05f;

        bool hit = (cx + rx >= x0c) && (cx - rx <= x1c) &&
                   (cy + ry >= y0c) && (cy - ry <= y1c);
        if (hit) {
            int slot = atomicAdd(&s_cnt, 1);
            if (slot < MAXG) {
                cA[slot] = make_float4(cx, cy, ca, cb);
                cB[slot] = make_float4(cc, op, feat[3 * i], feat[3 * i + 1]);
                cC[slot] = feat[3 * i + 2];
            }
        }
    }
    __syncthreads();
    const int cnt = min(s_cnt, MAXG);

    // ---- render this thread's pixel ----
    const int lx = tid & 15;
    const int ly = tid >> 4;
    const int x = tx * TILE + lx;
    const int y = ty * TILE + ly;
    const float px = (float)x + 0.5f;
    const float py = (float)y + 0.5f;

    float accr = 0.0f, accg = 0.0f, accb = 0.0f;
    for (int j = 0; j < cnt; ++j) {
        float4 A = cA[j];            // broadcast reads (uniform index)
        float4 B = cB[j];
        float fb = cC[j];
        float dx = A.x - px;
        float dy = A.y - py;
        // keep reference association: 0.5*(ca*dx*dx + cc*dy*dy) + cb*dx*dy
        float sigma = 0.5f * (A.z * dx * dx + B.x * dy * dy) + A.w * dx * dy;
        float alpha = fminf(0.999f, B.y * __expf(-sigma));
        float w = (sigma >= 0.0f && alpha >= ALPHA_T) ? alpha : 0.0f;
        accr = fmaf(w, B.z, accr);
        accg = fmaf(w, B.w, accg);
        accb = fmaf(w, fb, accb);
    }

    const int p = y * WW + x;
    out[p]                 = fminf(fmaxf(accr, 0.0f), 1.0f);
    out[HH * WW + p]       = fminf(fmaxf(accg, 0.0f), 1.0f);
    out[2 * HH * WW + p]   = fminf(fmaxf(accb, 0.0f), 1.0f);
}

extern "C" void kernel_launch(void* const* d_in, const int* in_sizes, int n_in,
                              void* d_out, int out_size, void* d_ws, size_t ws_size,
                              hipStream_t stream) {
    const float* xyz  = (const float*)d_in[0];
    const float* chol = (const float*)d_in[1];
    const float* feat = (const float*)d_in[2];
    const float* opac = (const float*)d_in[3];
    float* out = (float*)d_out;
    const int N = in_sizes[0] / 2;

    gsplat_render<<<dim3(256), dim3(256), 0, stream>>>(xyz, chol, feat, opac, out, N);
}